// Round 4
// baseline (36.051 us; speedup 1.0000x reference)
//
#include <hip/hip_runtime.h>

#define N_PED 2048
#define SEQ 8
#define NW 64        // 32-bit words per column bitmask (2048/32)
#define NBLK 256     // 1 block/CU (128 KB LDS), co-resident by construction

// ws layout (cleared each call by init_kernel; ck fully overwritten, no clear):
#define OFF_SUM64  (512 * 1024)   // colmask: [0, 512K)
#define OFF_MINROW (528 * 1024)   // sum64:   [512K, 528K)
#define OFF_BAR    (536 * 1024)   // minrow:  [528K, 536K)
#define OFF_CK     (540 * 1024)   // bar:     [536K, 540K); ck: [540K, 548K)
#define WS_CLEAR_BYTES (540 * 1024)

#define AGENT __HIP_MEMORY_SCOPE_AGENT

// ---------------------------------------------------------------------------
// Kernel 0: clear ws (colmask+sum64+minrow+barrier) + v -> out straight-through
// copy. 135 blocks x 256 threads: 34560 float4 clear, 8192 float4 copy.
// Kernel boundary makes these writes device-visible to the fused kernel.
// ---------------------------------------------------------------------------
__global__ __launch_bounds__(256) void init_kernel(const float* __restrict__ v,
                                                   float4* __restrict__ ws4,
                                                   float* __restrict__ out) {
    const int g = blockIdx.x * 256 + threadIdx.x;
    if (g < WS_CLEAR_BYTES / 16) ws4[g] = make_float4(0.f, 0.f, 0.f, 0.f);
    if (g < (2 * SEQ * N_PED) / 4) ((float4*)out)[g] = ((const float4*)v)[g];
}

// ---------------------------------------------------------------------------
// Fused kernel: edges phase (256 blocks x 8 waves, one row per wave, perfectly
// balanced: SIMD s hosts rows {4b+s, 2047-4b-s} -> 2047 cols per SIMD exactly)
// -> software grid barrier -> scan phase on block 0 only.
// Per-pair arithmetic bit-identical to the verified rounds.
// ---------------------------------------------------------------------------
__global__ __launch_bounds__(512) void fused_kernel(const float* __restrict__ va,
                                                    unsigned* colmask,
                                                    unsigned long long* sum64,
                                                    unsigned* minrow_enc,
                                                    int* ck,
                                                    int* bar,
                                                    float* __restrict__ out) {
    __shared__ float lds[16 * N_PED];   // 128 KB; reused by scan phase
    const int tid  = threadIdx.x;
    const int lane = tid & 63;
    const int w    = tid >> 6;
    const int b    = blockIdx.x;
    const int r    = (w < 4) ? (4 * b + w) : (2047 - 4 * b - (w - 4));

    // ---- stage columns [0, SC) of all 16 planes into LDS ----
    const int lmax = 2047 - 4 * b;
    const int SC   = (lmax + 63) & ~63;
    const int CL4  = SC >> 2;
    for (int p = 0; p < 16; ++p) {
        const float4* src = (const float4*)va + p * (N_PED / 4);
        float4* dst = (float4*)(lds + p * N_PED);
        for (int j = tid; j < CL4; j += 512) dst[j] = src[j];
    }
    __syncthreads();

    float xr[SEQ], yr[SEQ];
#pragma unroll
    for (int t = 0; t < SEQ; ++t) {
        xr[t] = va[t * N_PED + r];
        yr[t] = va[(SEQ + t) * N_PED + r];
    }

    int maxc = -1;
    const int ng = (r + 63) >> 6;
    for (int k = 0; k < ng; ++k) {
        const int c = (k << 6) + lane;
        float dsum = 0.0f;
#pragma unroll
        for (int t = 0; t < SEQ; ++t) {
            const float dx = xr[t] - lds[t * N_PED + c];
            const float dy = yr[t] - lds[(SEQ + t) * N_PED + c];
            const float s = __fadd_rn(__fmul_rn(dx, dx), __fmul_rn(dy, dy));
            const float d = (s > 0.0f) ? __fsqrt_rn(s) : 0.0f;
            dsum = __fadd_rn(dsum, d);
        }
        const float dist = dsum * 0.125f;
        if ((dist <= 1.0f) && (c < r)) {
            atomicOr(&colmask[c * NW + (r >> 5)], 1u << (r & 31));
            atomicOr(&sum64[c], 1ull << (r >> 5));
            atomicMax(&minrow_enc[c], (unsigned)(N_PED - r));
            maxc = c;
        }
    }
#pragma unroll
    for (int off = 32; off >= 1; off >>= 1)
        maxc = max(maxc, __shfl_xor(maxc, off, 64));
    if (lane == 0)
        __hip_atomic_store(&ck[r], maxc, __ATOMIC_RELAXED, AGENT);  // device-visible

    // ---- software grid barrier (all 256 blocks co-resident: 128KB LDS = 1/CU) ----
    __syncthreads();              // drains this block's vmem (incl. atomics) first
    if (tid == 0) {
        __hip_atomic_fetch_add(bar, 1, __ATOMIC_ACQ_REL, AGENT);
        if (b == 0)
            while (__hip_atomic_load(bar, __ATOMIC_ACQUIRE, AGENT) < NBLK)
                __builtin_amdgcn_s_sleep(2);
    }
    if (b != 0) return;
    __syncthreads();

    // =========================== scan phase (block 0) ===========================
    int* ckL    = (int*)lds;             // [2048]
    int* succL  = ckL + N_PED;           // [2048]
    int* labelL = succL + N_PED;         // [2048]
    int* cumL   = labelL + N_PED;        // [2048]
    unsigned long long* sumL = (unsigned long long*)(cumL + N_PED);  // [2048], 8B-aligned
    int* waveS  = (int*)(sumL + N_PED);  // [8]
    const int t = tid;

    for (int i = t; i < N_PED; i += 512) {
        ckL[i]  = __hip_atomic_load(&ck[i], __ATOMIC_RELAXED, AGENT);
        sumL[i] = __hip_atomic_load(&sum64[i], __ATOMIC_RELAXED, AGENT);
    }
    __syncthreads();

    // successor of incarnation created at active row i: first bit > i in column
    // ck[i] (summary word -> at most 2 coherent word loads); terminal -> self
    for (int i = t; i < N_PED; i += 512) {
        int s = i;
        const int c = ckL[i];
        if (c >= 0 && i + 1 < N_PED) {
            const int start = i + 1;
            const int w0 = start >> 5;
            const unsigned long long sum = sumL[c];
            unsigned bits = 0u;
            if ((sum >> w0) & 1ull)
                bits = __hip_atomic_load(&colmask[c * NW + w0], __ATOMIC_RELAXED, AGENT)
                       & (0xFFFFFFFFu << (start & 31));
            if (bits) s = (w0 << 5) + __ffs(bits) - 1;
            else {
                const unsigned long long rem = (w0 < 63) ? (sum & (~0ull << (w0 + 1))) : 0ull;
                if (rem) {
                    const int w2 = __ffsll(rem) - 1;
                    s = (w2 << 5) +
                        __ffs(__hip_atomic_load(&colmask[c * NW + w2], __ATOMIC_RELAXED, AGENT)) - 1;
                }
            }
        }
        succL[i] = s;
    }
    __syncthreads();

    // pointer doubling: 2^11 >= 2048 covers max chain length (4 elems/thread)
    for (int it = 0; it < 11; ++it) {
        const int a0 = succL[succL[t]];
        const int a1 = succL[succL[t + 512]];
        const int a2 = succL[succL[t + 1024]];
        const int a3 = succL[succL[t + 1536]];
        __syncthreads();
        succL[t] = a0; succL[t + 512] = a1; succL[t + 1024] = a2; succL[t + 1536] = a3;
        __syncthreads();
    }

    // labels: active row -> ck at its chain terminal; inactive -> via minrow
    for (int i = t; i < N_PED; i += 512) {
        int fo;
        if (ckL[i] >= 0) fo = i;
        else {
            const unsigned enc = __hip_atomic_load(&minrow_enc[i], __ATOMIC_RELAXED, AGENT);
            fo = (enc == 0u) ? -1 : (int)(N_PED - enc);
        }
        labelL[i] = (fo < 0) ? i : ckL[succL[fo]];
        cumL[i] = 0;
    }
    __syncthreads();
    for (int i = t; i < N_PED; i += 512) cumL[labelL[i]] = 1;  // present flags
    __syncthreads();

    // inclusive prefix sum over cumL[2048]: 4 elems/thread, wave scan + offsets
    const int lane2 = t & 63, wid2 = t >> 6;   // 8 waves
    const int e0 = cumL[4 * t], e1 = cumL[4 * t + 1], e2 = cumL[4 * t + 2], e3 = cumL[4 * t + 3];
    const int ps = e0 + e1 + e2 + e3;
    int sc = ps;
#pragma unroll
    for (int off = 1; off < 64; off <<= 1) {
        const int n = __shfl_up(sc, off, 64);
        if (lane2 >= off) sc += n;
    }
    if (lane2 == 63) waveS[wid2] = sc;
    __syncthreads();
    if (t == 0) {
        int acc = 0;
        for (int wv = 0; wv < 8; ++wv) { const int x = waveS[wv]; waveS[wv] = acc; acc += x; }
    }
    __syncthreads();
    int base = waveS[wid2] + (sc - ps);
    cumL[4 * t]     = base + e0;
    cumL[4 * t + 1] = base + e0 + e1;
    cumL[4 * t + 2] = base + e0 + e1 + e2;
    cumL[4 * t + 3] = base + e0 + e1 + e2 + e3;
    __syncthreads();

    for (int i = t; i < N_PED; i += 512)
        out[2 * SEQ * N_PED + i] = (float)(cumL[labelL[i]] - 1);
}

extern "C" void kernel_launch(void* const* d_in, const int* in_sizes, int n_in,
                              void* d_out, int out_size, void* d_ws, size_t ws_size,
                              hipStream_t stream) {
    const float* v  = (const float*)d_in[0];
    const float* va = (const float*)d_in[1];
    float* out = (float*)d_out;
    char* ws = (char*)d_ws;

    unsigned* colmask         = (unsigned*)ws;
    unsigned long long* sum64 = (unsigned long long*)(ws + OFF_SUM64);
    unsigned* minrow_enc      = (unsigned*)(ws + OFF_MINROW);
    int* bar                  = (int*)(ws + OFF_BAR);
    int* ck                   = (int*)(ws + OFF_CK);

    init_kernel<<<135, 256, 0, stream>>>(v, (float4*)ws, out);
    fused_kernel<<<NBLK, 512, 0, stream>>>(va, colmask, sum64, minrow_enc, ck, bar, out);
}

// Round 5
// 33.683 us; speedup vs baseline: 1.0703x; 1.0703x over previous
//
#include <hip/hip_runtime.h>

#define N_PED 2048
#define SEQ 8
#define NG 32    // 64-bit row-groups per column (2048/64)

// ws layout — NOTHING is cleared; every word is direct-stored each call:
//   colmask64 : 2048 cols * 32 u64 = 512 KB  (bit (r&63) of word (r>>6) <=> edge (r,c), r>c)
//   meta      : 2048 int4          =  32 KB  {ck, minrow, sum32, 0}
// No atomics anywhere -> poison/garbage-proof and replay-idempotent by construction.

// ---------------------------------------------------------------------------
// Kernel 1: dual-ownership sweep. 256 blocks x 512 threads; wave w of block b
// owns index i = 8b+w and evaluates dist(i,j) for ALL j (2047 real pairs —
// perfectly uniform load). j<i => row side (ck[i] via ballot-max);
// j>i => column side (colmask64[i], summary, minrow) — all direct stores.
// Per-pair arithmetic bit-identical to verified rounds:
//   dist = 0.125 * sum_t sqrt((xi-xj)^2+(yi-yj)^2), threshold dist<=1
//   (compared as dsum<=8.0, exact since *0.125 is an exponent shift;
//    s>0 guard dropped since __fsqrt_rn(+0)=+0 exactly).
// ---------------------------------------------------------------------------
__global__ __launch_bounds__(512) void dual_kernel(const float* __restrict__ va,
                                                   const float* __restrict__ v,
                                                   unsigned long long* __restrict__ colmask64,
                                                   int4* __restrict__ meta,
                                                   float* __restrict__ out) {
    __shared__ float2 lds2[SEQ * N_PED];   // 128 KB: (x,y) interleaved per timestep
    const int tid  = threadIdx.x;
    const int lane = tid & 63;
    const int w    = tid >> 6;
    const int b    = blockIdx.x;
    const int i    = b * 8 + w;

    // straight-through v -> out[0:32768], 32 float4 per block
    if (tid < 32) ((float4*)out)[b * 32 + tid] = ((const float4*)v)[b * 32 + tid];

    // stage interleaved (x,y): one float4 of x-plane + one of y-plane per thread per t
    for (int t = 0; t < SEQ; ++t) {
        const float4 x4 = ((const float4*)va)[t * (N_PED / 4) + tid];
        const float4 y4 = ((const float4*)va)[(SEQ + t) * (N_PED / 4) + tid];
        float4* dst = (float4*)(lds2 + t * N_PED + tid * 4);
        dst[0] = make_float4(x4.x, y4.x, x4.y, y4.y);
        dst[1] = make_float4(x4.z, y4.z, x4.w, y4.w);
    }

    float xr[SEQ], yr[SEQ];
#pragma unroll
    for (int t = 0; t < SEQ; ++t) {
        xr[t] = va[t * N_PED + i];
        yr[t] = va[(SEQ + t) * N_PED + i];
    }
    __syncthreads();

    const int ig = i >> 6, il = i & 63;
    unsigned long long mygt = 0ull;   // lane k (<32) keeps group k's column word
    unsigned sum = 0u;
    int mr = -1, mc = -1;

    for (int k = 0; k < NG; ++k) {
        float dsum = 0.0f;
#pragma unroll
        for (int t = 0; t < SEQ; ++t) {
            const float2 p = lds2[t * N_PED + (k << 6) + lane];
            const float dx = xr[t] - p.x;
            const float dy = yr[t] - p.y;
            const float s = __fadd_rn(__fmul_rn(dx, dx), __fmul_rn(dy, dy));
            dsum = __fadd_rn(dsum, __fsqrt_rn(s));
        }
        const unsigned long long bal = __ballot(dsum <= 8.0f);
        unsigned long long lt, gt;
        if (k < ig)      { lt = bal;  gt = 0ull; }
        else if (k > ig) { lt = 0ull; gt = bal;  }
        else {
            lt = il ? (bal & ((1ull << il) - 1ull)) : 0ull;
            gt = (il == 63) ? 0ull : (bal & (~0ull << (il + 1)));
        }
        if (lt) mc = (k << 6) + 63 - __clzll(lt);          // last j<i, groups ascend
        if (gt) { sum |= (1u << k); if (mr < 0) mr = (k << 6) + __ffsll(gt) - 1; }
        if (lane == k) mygt = gt;
    }

    if (lane < 32) colmask64[i * NG + lane] = mygt;        // one coalesced 256B store
    if (lane == 0) meta[i] = make_int4(mc, mr, (int)sum, 0);
}

// ---------------------------------------------------------------------------
// Kernel 2 (single block, 1024 threads): static successors via summary words
// (<=2 global u64 loads per active row), pointer doubling w/ early exit,
// labels, rank remap. Plain loads (kernel boundary flushed remote L2s).
// ---------------------------------------------------------------------------
__global__ __launch_bounds__(1024) void scan_kernel(const unsigned long long* __restrict__ colmask64,
                                                    const int4* __restrict__ meta,
                                                    float* __restrict__ out) {
    __shared__ int ckL[N_PED];
    __shared__ int succL[N_PED];
    __shared__ int labelL[N_PED];
    __shared__ int cumL[N_PED];
    __shared__ int mrL[N_PED];
    __shared__ unsigned sumL[N_PED];
    __shared__ int waveS[16];
    const int t = threadIdx.x;

    for (int i = t; i < N_PED; i += 1024) {
        const int4 m = meta[i];
        ckL[i] = m.x; mrL[i] = m.y; sumL[i] = (unsigned)m.z;
    }
    __syncthreads();

    // successor of incarnation created at active row i: first bit > i in
    // column ck[i]; terminal (or inactive) -> self
    for (int i = t; i < N_PED; i += 1024) {
        int s = i;
        const int c = ckL[i];
        if (c >= 0 && i + 1 < N_PED) {
            const int start = i + 1;
            const int g0 = start >> 6;
            const unsigned sum = sumL[c];
            unsigned long long bits = 0ull;
            if ((sum >> g0) & 1u)
                bits = colmask64[c * NG + g0] & (~0ull << (start & 63));
            if (bits) s = (g0 << 6) + __ffsll(bits) - 1;
            else {
                const unsigned rem = (g0 < 31) ? (sum & (~0u << (g0 + 1))) : 0u;
                if (rem) {
                    const int g2 = __ffs(rem) - 1;
                    s = (g2 << 6) + __ffsll(colmask64[c * NG + g2]) - 1;
                }
            }
        }
        succL[i] = s;
    }
    __syncthreads();

    // pointer doubling (2^11 >= 2048 worst case) with convergence early-exit
    for (int it = 0; it < 11; ++it) {
        const int s0 = succL[t], s1 = succL[t + 1024];
        const int a0 = succL[s0], a1 = succL[s1];
        __syncthreads();
        succL[t] = a0; succL[t + 1024] = a1;
        if (__syncthreads_count((a0 != s0) || (a1 != s1)) == 0) break;
    }

    // labels: active row -> ck at chain terminal; inactive -> via column minrow
    for (int i = t; i < N_PED; i += 1024) {
        const int fo = (ckL[i] >= 0) ? i : mrL[i];
        labelL[i] = (fo < 0) ? i : ckL[succL[fo]];
        cumL[i] = 0;
    }
    __syncthreads();
    for (int i = t; i < N_PED; i += 1024) cumL[labelL[i]] = 1;   // present flags
    __syncthreads();

    // inclusive prefix sum over cumL[2048]: 2 elems/thread, wave scan + offsets
    const int lane = t & 63, wid = t >> 6;
    const int e0 = cumL[2 * t], e1 = cumL[2 * t + 1];
    const int ps = e0 + e1;
    int sc = ps;
#pragma unroll
    for (int off = 1; off < 64; off <<= 1) {
        const int n = __shfl_up(sc, off, 64);
        if (lane >= off) sc += n;
    }
    if (lane == 63) waveS[wid] = sc;
    __syncthreads();
    if (t == 0) {
        int acc = 0;
        for (int wv = 0; wv < 16; ++wv) { const int x = waveS[wv]; waveS[wv] = acc; acc += x; }
    }
    __syncthreads();
    const int base = waveS[wid] + (sc - ps);
    cumL[2 * t]     = base + e0;
    cumL[2 * t + 1] = base + e0 + e1;
    __syncthreads();

    for (int i = t; i < N_PED; i += 1024)
        out[2 * SEQ * N_PED + i] = (float)(cumL[labelL[i]] - 1);
}

extern "C" void kernel_launch(void* const* d_in, const int* in_sizes, int n_in,
                              void* d_out, int out_size, void* d_ws, size_t ws_size,
                              hipStream_t stream) {
    const float* v  = (const float*)d_in[0];
    const float* va = (const float*)d_in[1];
    float* out = (float*)d_out;
    char* ws = (char*)d_ws;

    unsigned long long* colmask64 = (unsigned long long*)ws;          // 512 KB
    int4* meta                    = (int4*)(ws + 512 * 1024);         //  32 KB

    dual_kernel<<<N_PED / 8, 512, 0, stream>>>(va, v, colmask64, meta, out);
    scan_kernel<<<1, 1024, 0, stream>>>(colmask64, meta, out);
}

// Round 6
// 31.136 us; speedup vs baseline: 1.1579x; 1.0818x over previous
//
#include <hip/hip_runtime.h>

#define N_PED 2048
#define SEQ 8
#define NG 32    // 64-bit row-groups per column (2048/64)

// ws layout — no clears needed:
//   colmask64 : 2048 cols * 32 u64 = 512 KB  (bit (r&63) of word (r>>6) <=> edge (r,c), r>c)
//               direct full-overwrite stores every call (sub-diagonal words stored as 0)
//   meta      : 2048 int2          =  16 KB  {minrow, sum32} — direct stores
//   ck        : 2048 int           =   8 KB  — atomicMax only; poison 0xAAAAAAAA is a huge
//               negative int and every index is floored via atomicMax(ck[c], -1) by its own
//               column wave => poison-proof AND replay-idempotent (max is monotone).

// ---------------------------------------------------------------------------
// Kernel 1: column-ownership triangle sweep. 256 blocks x 512 threads.
// Wave w<4 owns column c=4b+w; wave w>=4 owns c=2047-4b-(w-4). SIMD s hosts
// {4b+s, 2047-4b-s}: group-iters per SIMD = (32-g) + (g+1) = 33 exactly ->
// perfect static balance, HALF the pair-evals of the dual-ownership sweep.
// For column c it evaluates rows r>c only; ballot gives the column word for
// a whole 64-row group at once. Per-pair arithmetic bit-identical to the
// verified rounds: dsum = sum_t sqrt_rn(fadd(fmul(dx,dx),fmul(dy,dy))),
// edge iff dsum <= 8.0f (== mean*0.125 <= 1.0 exactly).
// ---------------------------------------------------------------------------
__global__ __launch_bounds__(512) void col_kernel(const float* __restrict__ va,
                                                  const float* __restrict__ v,
                                                  unsigned long long* __restrict__ colmask64,
                                                  int2* __restrict__ meta,
                                                  int* __restrict__ ck,
                                                  float* __restrict__ out) {
    __shared__ float2 lds2[SEQ * N_PED];   // <=128 KB used: [SEQ][NS] (x,y) interleaved
    const int tid  = threadIdx.x;
    const int lane = tid & 63;
    const int w    = tid >> 6;
    const int b    = blockIdx.x;
    const int c    = (w < 4) ? (4 * b + w) : (2047 - 4 * b - (w - 4));

    // straight-through v -> out[0:32768], 32 float4 per block
    if (tid < 32) ((float4*)out)[b * 32 + tid] = ((const float4*)v)[b * 32 + tid];

    // stage rows [RB, 2048) of all timesteps as interleaved (x,y)
    const int RB = (4 * b) & ~63;          // aligned row base (min column = 4b)
    const int NS = N_PED - RB;             // staged rows, multiple of 64
    for (int t = 0; t < SEQ; ++t) {
        const float4* xs = (const float4*)va + t * (N_PED / 4);
        const float4* ys = (const float4*)va + (SEQ + t) * (N_PED / 4);
        float4* dst = (float4*)(lds2 + t * NS);
        for (int j = tid; j < NS / 4; j += 512) {
            const float4 x4 = xs[RB / 4 + j];
            const float4 y4 = ys[RB / 4 + j];
            dst[2 * j]     = make_float4(x4.x, y4.x, x4.y, y4.y);
            dst[2 * j + 1] = make_float4(x4.z, y4.z, x4.w, y4.w);
        }
    }

    float xc[SEQ], yc[SEQ];
#pragma unroll
    for (int t = 0; t < SEQ; ++t) {
        xc[t] = va[t * N_PED + c];
        yc[t] = va[(SEQ + t) * N_PED + c];
    }
    __syncthreads();

    const int g0 = c >> 6, cl = c & 63;
    unsigned long long myw = 0ull;   // lane g keeps group g's column word (others 0)
    unsigned sum = 0u;
    int mr = -1;

    for (int g = g0; g < NG; ++g) {
        const int ri = (g << 6) + lane - RB;        // staged row index (>=0 by constr.)
        float dsum = 0.0f;
#pragma unroll
        for (int t = 0; t < SEQ; ++t) {
            const float2 p = lds2[t * NS + ri];
            const float dx = xc[t] - p.x;
            const float dy = yc[t] - p.y;
            const float s = __fadd_rn(__fmul_rn(dx, dx), __fmul_rn(dy, dy));
            dsum = __fadd_rn(dsum, __fsqrt_rn(s));
        }
        unsigned long long gt = __ballot(dsum <= 8.0f);
        if (g == g0) gt = (cl == 63) ? 0ull : (gt & (~0ull << (cl + 1)));  // rows > c only
        if (gt) { sum |= (1u << g); if (mr < 0) mr = (g << 6) + __ffsll(gt) - 1; }
        if (lane == g) myw = gt;
    }

    if (lane < 32) colmask64[c * NG + lane] = myw;          // one coalesced 256B store
    if (lane == 0) { meta[c] = make_int2(mr, (int)sum); atomicMax(&ck[c], -1); }

    // scatter row-side maxima: ck[r] = max c with edge (r,c)
    unsigned long long W = (lane < 32) ? myw : 0ull;
    while (W) {
        const int rr = (lane << 6) + __ffsll(W) - 1;
        atomicMax(&ck[rr], c);
        W &= W - 1ull;
    }
}

// ---------------------------------------------------------------------------
// Kernel 2 (single block, 1024 threads): static successors via summary words
// (<=2 global u64 loads per active row), pointer doubling w/ early exit,
// labels, rank remap. Plain loads (kernel boundary made colmask/ck visible).
// ---------------------------------------------------------------------------
__global__ __launch_bounds__(1024) void scan_kernel(const unsigned long long* __restrict__ colmask64,
                                                    const int2* __restrict__ meta,
                                                    const int* __restrict__ ck,
                                                    float* __restrict__ out) {
    __shared__ int ckL[N_PED];
    __shared__ int succL[N_PED];
    __shared__ int labelL[N_PED];
    __shared__ int cumL[N_PED];
    __shared__ int mrL[N_PED];
    __shared__ unsigned sumL[N_PED];
    __shared__ int waveS[16];
    const int t = threadIdx.x;

    for (int i = t; i < N_PED; i += 1024) {
        const int2 m = meta[i];
        ckL[i] = ck[i]; mrL[i] = m.x; sumL[i] = (unsigned)m.y;
    }
    __syncthreads();

    // successor of incarnation created at active row i: first bit > i in
    // column ck[i]; terminal (or inactive) -> self
    for (int i = t; i < N_PED; i += 1024) {
        int s = i;
        const int c = ckL[i];
        if (c >= 0 && i + 1 < N_PED) {
            const int start = i + 1;
            const int g0 = start >> 6;
            const unsigned sum = sumL[c];
            unsigned long long bits = 0ull;
            if ((sum >> g0) & 1u)
                bits = colmask64[c * NG + g0] & (~0ull << (start & 63));
            if (bits) s = (g0 << 6) + __ffsll(bits) - 1;
            else {
                const unsigned rem = (g0 < 31) ? (sum & (~0u << (g0 + 1))) : 0u;
                if (rem) {
                    const int g2 = __ffs(rem) - 1;
                    s = (g2 << 6) + __ffsll(colmask64[c * NG + g2]) - 1;
                }
            }
        }
        succL[i] = s;
    }
    __syncthreads();

    // pointer doubling (2^11 >= 2048 worst case) with convergence early-exit
    for (int it = 0; it < 11; ++it) {
        const int s0 = succL[t], s1 = succL[t + 1024];
        const int a0 = succL[s0], a1 = succL[s1];
        __syncthreads();
        succL[t] = a0; succL[t + 1024] = a1;
        if (__syncthreads_count((a0 != s0) || (a1 != s1)) == 0) break;
    }

    // labels: active row -> ck at chain terminal; inactive -> via column minrow
    for (int i = t; i < N_PED; i += 1024) {
        const int fo = (ckL[i] >= 0) ? i : mrL[i];
        labelL[i] = (fo < 0) ? i : ckL[succL[fo]];
        cumL[i] = 0;
    }
    __syncthreads();
    for (int i = t; i < N_PED; i += 1024) cumL[labelL[i]] = 1;   // present flags
    __syncthreads();

    // inclusive prefix sum over cumL[2048]: 2 elems/thread, wave scan + offsets
    const int lane = t & 63, wid = t >> 6;
    const int e0 = cumL[2 * t], e1 = cumL[2 * t + 1];
    const int ps = e0 + e1;
    int sc = ps;
#pragma unroll
    for (int off = 1; off < 64; off <<= 1) {
        const int n = __shfl_up(sc, off, 64);
        if (lane >= off) sc += n;
    }
    if (lane == 63) waveS[wid] = sc;
    __syncthreads();
    if (t == 0) {
        int acc = 0;
        for (int wv = 0; wv < 16; ++wv) { const int x = waveS[wv]; waveS[wv] = acc; acc += x; }
    }
    __syncthreads();
    const int base = waveS[wid] + (sc - ps);
    cumL[2 * t]     = base + e0;
    cumL[2 * t + 1] = base + e0 + e1;
    __syncthreads();

    for (int i = t; i < N_PED; i += 1024)
        out[2 * SEQ * N_PED + i] = (float)(cumL[labelL[i]] - 1);
}

extern "C" void kernel_launch(void* const* d_in, const int* in_sizes, int n_in,
                              void* d_out, int out_size, void* d_ws, size_t ws_size,
                              hipStream_t stream) {
    const float* v  = (const float*)d_in[0];
    const float* va = (const float*)d_in[1];
    float* out = (float*)d_out;
    char* ws = (char*)d_ws;

    unsigned long long* colmask64 = (unsigned long long*)ws;          // 512 KB
    int2* meta                    = (int2*)(ws + 512 * 1024);         //  16 KB
    int* ck                       = (int*)(ws + 528 * 1024);          //   8 KB

    col_kernel<<<N_PED / 8, 512, 0, stream>>>(va, v, colmask64, meta, ck, out);
    scan_kernel<<<1, 1024, 0, stream>>>(colmask64, meta, ck, out);
}

// Round 7
// 27.380 us; speedup vs baseline: 1.3167x; 1.1372x over previous
//
#include <hip/hip_runtime.h>

#define N_PED 2048
#define SEQ 8
#define NG 32    // 64-bit row-groups per column (2048/64)

// ws layout — no clears needed:
//   colmask64 : 2048 cols * 32 u64 = 512 KB  (bit (r&63) of word (r>>6) <=> edge (r,c), r>c)
//               direct full-overwrite stores every call (sub-diagonal words stored as 0)
//   meta      : 2048 int2          =  16 KB  {minrow, sum32} — direct stores
//   ck        : 2048 int           =   8 KB  — atomicMax only; poison 0xAAAAAAAA is a huge
//               negative int and every index is floored via atomicMax(ck[c], -1) by its own
//               column wave => poison-proof AND replay-idempotent (max is monotone).

// ---------------------------------------------------------------------------
// Kernel 1: column-ownership triangle sweep. 256 blocks x 512 threads.
// Wave w<4 owns column c=4b+w; wave w>=4 owns c=2047-4b-(w-4). SIMD s hosts
// {4b+s, 2047-4b-s}: group-iters per SIMD = (32-g) + (g+1) = 33 exactly ->
// perfect static balance. For column c: rows r>c only; ballot gives the
// column word for a 64-row group at once.
// Edge set bit-identical to verified rounds: edge iff dsum <= 8.0 where
// dsum = sequential fadd_rn chain over t of sqrt_rn(fadd(fmul(dx,dx),fmul(dy,dy))).
// FAST PATH: raw v_sqrt_f32 (<=1 ULP); if |dsum-8| <= 1e-3 (|fast-exact| < 1e-4,
// 10x margin) recompute dsum exactly from the saved exact s_t in reference order.
// ---------------------------------------------------------------------------
__global__ __launch_bounds__(512) void col_kernel(const float* __restrict__ va,
                                                  const float* __restrict__ v,
                                                  unsigned long long* __restrict__ colmask64,
                                                  int2* __restrict__ meta,
                                                  int* __restrict__ ck,
                                                  float* __restrict__ out) {
    __shared__ float2 lds2[SEQ * N_PED];   // <=128 KB used: [SEQ][NS] (x,y) interleaved
    const int tid  = threadIdx.x;
    const int lane = tid & 63;
    const int w    = tid >> 6;
    const int b    = blockIdx.x;
    const int c    = (w < 4) ? (4 * b + w) : (2047 - 4 * b - (w - 4));

    // straight-through v -> out[0:32768], 32 float4 per block
    if (tid < 32) ((float4*)out)[b * 32 + tid] = ((const float4*)v)[b * 32 + tid];

    // stage rows [RB, 2048) of all timesteps as interleaved (x,y)
    const int RB = (4 * b) & ~63;          // aligned row base (min column = 4b)
    const int NS = N_PED - RB;             // staged rows, multiple of 64
    for (int t = 0; t < SEQ; ++t) {
        const float4* xs = (const float4*)va + t * (N_PED / 4);
        const float4* ys = (const float4*)va + (SEQ + t) * (N_PED / 4);
        float4* dst = (float4*)(lds2 + t * NS);
        for (int j = tid; j < NS / 4; j += 512) {
            const float4 x4 = xs[RB / 4 + j];
            const float4 y4 = ys[RB / 4 + j];
            dst[2 * j]     = make_float4(x4.x, y4.x, x4.y, y4.y);
            dst[2 * j + 1] = make_float4(x4.z, y4.z, x4.w, y4.w);
        }
    }

    float xc[SEQ], yc[SEQ];
#pragma unroll
    for (int t = 0; t < SEQ; ++t) {
        xc[t] = va[t * N_PED + c];
        yc[t] = va[(SEQ + t) * N_PED + c];
    }
    __syncthreads();

    const int g0 = c >> 6, cl = c & 63;
    unsigned long long myw = 0ull;   // lane g keeps group g's column word (others 0)
    unsigned sum = 0u;
    int mr = -1;

    for (int g = g0; g < NG; ++g) {
        const int ri = (g << 6) + lane - RB;        // staged row index (>=0 by constr.)
        float s8[SEQ];
        float dsum = 0.0f;
#pragma unroll
        for (int t = 0; t < SEQ; ++t) {
            const float2 p = lds2[t * NS + ri];
            const float dx = xc[t] - p.x;
            const float dy = yc[t] - p.y;
            const float s = __fadd_rn(__fmul_rn(dx, dx), __fmul_rn(dy, dy));
            s8[t] = s;
            dsum = __fadd_rn(dsum, __builtin_amdgcn_sqrtf(s));   // raw v_sqrt_f32
        }
        if (__builtin_expect(__builtin_fabsf(dsum - 8.0f) <= 1e-3f, 0)) {
            // exact recompute in reference order (rare: near-threshold lanes only)
            dsum = 0.0f;
#pragma unroll
            for (int t = 0; t < SEQ; ++t) dsum = __fadd_rn(dsum, __fsqrt_rn(s8[t]));
        }
        unsigned long long gt = __ballot(dsum <= 8.0f);
        if (g == g0) gt = (cl == 63) ? 0ull : (gt & (~0ull << (cl + 1)));  // rows > c only
        if (gt) { sum |= (1u << g); if (mr < 0) mr = (g << 6) + __ffsll(gt) - 1; }
        if (lane == g) myw = gt;
    }

    if (lane < 32) colmask64[c * NG + lane] = myw;          // one coalesced 256B store
    if (lane == 0) { meta[c] = make_int2(mr, (int)sum); atomicMax(&ck[c], -1); }

    // scatter row-side maxima: ck[r] = max c with edge (r,c)
    unsigned long long W = (lane < 32) ? myw : 0ull;
    while (W) {
        const int rr = (lane << 6) + __ffsll(W) - 1;
        atomicMax(&ck[rr], c);
        W &= W - 1ull;
    }
}

// ---------------------------------------------------------------------------
// Kernel 2 (single block, 1024 threads): static successors via summary words
// (<=2 global u64 loads per active row), pointer doubling w/ early exit,
// labels, rank remap. Plain loads (kernel boundary made colmask/ck visible).
// ---------------------------------------------------------------------------
__global__ __launch_bounds__(1024) void scan_kernel(const unsigned long long* __restrict__ colmask64,
                                                    const int2* __restrict__ meta,
                                                    const int* __restrict__ ck,
                                                    float* __restrict__ out) {
    __shared__ int ckL[N_PED];
    __shared__ int succL[N_PED];
    __shared__ int labelL[N_PED];
    __shared__ int cumL[N_PED];
    __shared__ int mrL[N_PED];
    __shared__ unsigned sumL[N_PED];
    __shared__ int waveS[16];
    const int t = threadIdx.x;

    for (int i = t; i < N_PED; i += 1024) {
        const int2 m = meta[i];
        ckL[i] = ck[i]; mrL[i] = m.x; sumL[i] = (unsigned)m.y;
    }
    __syncthreads();

    // successor of incarnation created at active row i: first bit > i in
    // column ck[i]; terminal (or inactive) -> self
    for (int i = t; i < N_PED; i += 1024) {
        int s = i;
        const int c = ckL[i];
        if (c >= 0 && i + 1 < N_PED) {
            const int start = i + 1;
            const int g0 = start >> 6;
            const unsigned sum = sumL[c];
            unsigned long long bits = 0ull;
            if ((sum >> g0) & 1u)
                bits = colmask64[c * NG + g0] & (~0ull << (start & 63));
            if (bits) s = (g0 << 6) + __ffsll(bits) - 1;
            else {
                const unsigned rem = (g0 < 31) ? (sum & (~0u << (g0 + 1))) : 0u;
                if (rem) {
                    const int g2 = __ffs(rem) - 1;
                    s = (g2 << 6) + __ffsll(colmask64[c * NG + g2]) - 1;
                }
            }
        }
        succL[i] = s;
    }
    __syncthreads();

    // pointer doubling (2^11 >= 2048 worst case) with convergence early-exit
    for (int it = 0; it < 11; ++it) {
        const int s0 = succL[t], s1 = succL[t + 1024];
        const int a0 = succL[s0], a1 = succL[s1];
        __syncthreads();
        succL[t] = a0; succL[t + 1024] = a1;
        if (__syncthreads_count((a0 != s0) || (a1 != s1)) == 0) break;
    }

    // labels: active row -> ck at chain terminal; inactive -> via column minrow
    for (int i = t; i < N_PED; i += 1024) {
        const int fo = (ckL[i] >= 0) ? i : mrL[i];
        labelL[i] = (fo < 0) ? i : ckL[succL[fo]];
        cumL[i] = 0;
    }
    __syncthreads();
    for (int i = t; i < N_PED; i += 1024) cumL[labelL[i]] = 1;   // present flags
    __syncthreads();

    // inclusive prefix sum over cumL[2048]: 2 elems/thread, wave scan + offsets
    const int lane = t & 63, wid = t >> 6;
    const int e0 = cumL[2 * t], e1 = cumL[2 * t + 1];
    const int ps = e0 + e1;
    int sc = ps;
#pragma unroll
    for (int off = 1; off < 64; off <<= 1) {
        const int n = __shfl_up(sc, off, 64);
        if (lane >= off) sc += n;
    }
    if (lane == 63) waveS[wid] = sc;
    __syncthreads();
    if (t == 0) {
        int acc = 0;
        for (int wv = 0; wv < 16; ++wv) { const int x = waveS[wv]; waveS[wv] = acc; acc += x; }
    }
    __syncthreads();
    const int base = waveS[wid] + (sc - ps);
    cumL[2 * t]     = base + e0;
    cumL[2 * t + 1] = base + e0 + e1;
    __syncthreads();

    for (int i = t; i < N_PED; i += 1024)
        out[2 * SEQ * N_PED + i] = (float)(cumL[labelL[i]] - 1);
}

extern "C" void kernel_launch(void* const* d_in, const int* in_sizes, int n_in,
                              void* d_out, int out_size, void* d_ws, size_t ws_size,
                              hipStream_t stream) {
    const float* v  = (const float*)d_in[0];
    const float* va = (const float*)d_in[1];
    float* out = (float*)d_out;
    char* ws = (char*)d_ws;

    unsigned long long* colmask64 = (unsigned long long*)ws;          // 512 KB
    int2* meta                    = (int2*)(ws + 512 * 1024);         //  16 KB
    int* ck                       = (int*)(ws + 528 * 1024);          //   8 KB

    col_kernel<<<N_PED / 8, 512, 0, stream>>>(va, v, colmask64, meta, ck, out);
    scan_kernel<<<1, 1024, 0, stream>>>(colmask64, meta, ck, out);
}

// Round 8
// 24.227 us; speedup vs baseline: 1.4881x; 1.1301x over previous
//
#include <hip/hip_runtime.h>

#define N_PED 2048
#define SEQ 8
#define NG 32    // 64-row groups per column (2048/64)

// ws layout — no clears, no colmask:
//   cand : 2048 int =  8 KB — atomicMax only. cand[r] = max over edge-columns c of
//          (c<<12)|succ_c(r), where succ_c(r) = next set bit of column c after r
//          (terminal -> r). Max is lexicographic in c => decode ck[r]=cand>>12,
//          succ[r]=cand&4095 for the MAX column = reference semantics.
//          Poison 0xAAAAAAAA is negative; every index floored via its own column
//          wave's atomicMax(&cand[c],0) => poison-proof + replay-idempotent.
//   mrA  : 2048 int =  8 KB — direct store: first set row of column c, or -1.

// ---------------------------------------------------------------------------
// Kernel 1: column-ownership triangle sweep (structure identical to R7's
// verified kernel). Wave w<4 owns c=4b+w; w>=4 owns 2047-4b-(w-4); 33
// group-iters/SIMD exactly. Edge set bit-identical: dsum<=8.0 with raw
// v_sqrt fast path + exact __fsqrt_rn recheck when |dsum-8|<=1e-3.
// New: instead of storing the column bitmask, emit per-edge packed
// (c<<12)|succ candidates via atomicMax (subsumes the old ck scatter).
// ---------------------------------------------------------------------------
__global__ __launch_bounds__(512) void col_kernel(const float* __restrict__ va,
                                                  const float* __restrict__ v,
                                                  int* __restrict__ cand,
                                                  int* __restrict__ mrA,
                                                  float* __restrict__ out) {
    __shared__ float2 lds2[SEQ * N_PED];   // <=128 KB: [SEQ][NS] (x,y) interleaved
    const int tid  = threadIdx.x;
    const int lane = tid & 63;
    const int w    = tid >> 6;
    const int b    = blockIdx.x;
    const int c    = (w < 4) ? (4 * b + w) : (2047 - 4 * b - (w - 4));

    // straight-through v -> out[0:32768], 32 float4 per block
    if (tid < 32) ((float4*)out)[b * 32 + tid] = ((const float4*)v)[b * 32 + tid];

    // stage rows [RB, 2048) of all timesteps as interleaved (x,y)
    const int RB = (4 * b) & ~63;          // aligned row base (min column = 4b)
    const int NS = N_PED - RB;             // staged rows, multiple of 64
    for (int t = 0; t < SEQ; ++t) {
        const float4* xs = (const float4*)va + t * (N_PED / 4);
        const float4* ys = (const float4*)va + (SEQ + t) * (N_PED / 4);
        float4* dst = (float4*)(lds2 + t * NS);
        for (int j = tid; j < NS / 4; j += 512) {
            const float4 x4 = xs[RB / 4 + j];
            const float4 y4 = ys[RB / 4 + j];
            dst[2 * j]     = make_float4(x4.x, y4.x, x4.y, y4.y);
            dst[2 * j + 1] = make_float4(x4.z, y4.z, x4.w, y4.w);
        }
    }

    float xc[SEQ], yc[SEQ];
#pragma unroll
    for (int t = 0; t < SEQ; ++t) {
        xc[t] = va[t * N_PED + c];
        yc[t] = va[(SEQ + t) * N_PED + c];
    }
    __syncthreads();

    const int g0 = c >> 6, cl = c & 63;
    unsigned long long myw = 0ull;   // lane g keeps group g's column word (others 0)

    for (int g = g0; g < NG; ++g) {
        const int ri = (g << 6) + lane - RB;        // staged row index (>=0 by constr.)
        float s8[SEQ];
        float dsum = 0.0f;
#pragma unroll
        for (int t = 0; t < SEQ; ++t) {
            const float2 p = lds2[t * NS + ri];
            const float dx = xc[t] - p.x;
            const float dy = yc[t] - p.y;
            const float s = __fadd_rn(__fmul_rn(dx, dx), __fmul_rn(dy, dy));
            s8[t] = s;
            dsum = __fadd_rn(dsum, __builtin_amdgcn_sqrtf(s));   // raw v_sqrt_f32
        }
        if (__builtin_expect(__builtin_fabsf(dsum - 8.0f) <= 1e-3f, 0)) {
            // exact recompute in reference order (rare: near-threshold lanes only)
            dsum = 0.0f;
#pragma unroll
            for (int t = 0; t < SEQ; ++t) dsum = __fadd_rn(dsum, __fsqrt_rn(s8[t]));
        }
        unsigned long long gt = __ballot(dsum <= 8.0f);
        if (g == g0) gt = (cl == 63) ? 0ull : (gt & (~0ull << (cl + 1)));  // rows > c only
        if (lane == g) myw = gt;
    }

    // ---- column successor emission (wave-uniform cross-lane setup) ----
    const unsigned long long nz = __ballot(myw != 0ull);          // nonzero word lanes
    const int fb = myw ? ((lane << 6) + __ffsll(myw) - 1) : -1;   // first abs row of my word
    const unsigned long long hi = (lane < 63) ? (nz & (~0ull << (lane + 1))) : 0ull;
    const int ngl = hi ? (__ffsll(hi) - 1) : 0;
    int nextfirst = __shfl(fb, ngl, 64);                          // first row of next nz word
    if (!hi) nextfirst = -1;
    const int fnl = nz ? (__ffsll(nz) - 1) : 0;
    int mr = __shfl(fb, fnl, 64);                                 // column minrow
    if (!nz) mr = -1;
    if (lane == 0) { mrA[c] = mr; atomicMax(&cand[c], 0); }       // direct store + poison floor

    unsigned long long W = myw;
    while (W) {
        const int r1 = (lane << 6) + __ffsll(W) - 1;
        W &= W - 1ull;
        const int r2 = W ? ((lane << 6) + __ffsll(W) - 1)
                         : (nextfirst >= 0 ? nextfirst : r1);     // terminal -> self
        atomicMax(&cand[r1], (c << 12) | r2);
    }
}

// ---------------------------------------------------------------------------
// Kernel 2 (single block, 1024 threads): 16 KB coalesced loads only — decode
// ck/succ from cand, pointer doubling w/ early exit, labels, rank remap.
// ---------------------------------------------------------------------------
__global__ __launch_bounds__(1024) void scan_kernel(const int* __restrict__ cand,
                                                    const int* __restrict__ mrA,
                                                    float* __restrict__ out) {
    __shared__ int ckL[N_PED];
    __shared__ int succL[N_PED];
    __shared__ int labelL[N_PED];
    __shared__ int cumL[N_PED];
    __shared__ int mrL[N_PED];
    __shared__ int waveS[16];
    const int t = threadIdx.x;

    for (int i = t; i < N_PED; i += 1024) {
        const int cd = cand[i];
        ckL[i]   = (cd > 0) ? (cd >> 12) : -1;      // max edge column of row i
        succL[i] = (cd > 0) ? (cd & 4095) : i;      // next bit in that column (self=terminal)
        mrL[i]   = mrA[i];                          // first row of column i (-1 if none)
    }
    __syncthreads();

    // pointer doubling (2^11 >= 2048 worst case) with convergence early-exit
    for (int it = 0; it < 11; ++it) {
        const int s0 = succL[t], s1 = succL[t + 1024];
        const int a0 = succL[s0], a1 = succL[s1];
        __syncthreads();
        succL[t] = a0; succL[t + 1024] = a1;
        if (__syncthreads_count((a0 != s0) || (a1 != s1)) == 0) break;
    }

    // labels: active row -> ck at chain terminal; inactive -> via column minrow
    for (int i = t; i < N_PED; i += 1024) {
        const int fo = (ckL[i] >= 0) ? i : mrL[i];
        labelL[i] = (fo < 0) ? i : ckL[succL[fo]];
        cumL[i] = 0;
    }
    __syncthreads();
    for (int i = t; i < N_PED; i += 1024) cumL[labelL[i]] = 1;   // present flags
    __syncthreads();

    // inclusive prefix sum over cumL[2048]: 2 elems/thread, wave scan + offsets
    const int lane = t & 63, wid = t >> 6;
    const int e0 = cumL[2 * t], e1 = cumL[2 * t + 1];
    const int ps = e0 + e1;
    int sc = ps;
#pragma unroll
    for (int off = 1; off < 64; off <<= 1) {
        const int n = __shfl_up(sc, off, 64);
        if (lane >= off) sc += n;
    }
    if (lane == 63) waveS[wid] = sc;
    __syncthreads();
    if (t == 0) {
        int acc = 0;
        for (int wv = 0; wv < 16; ++wv) { const int x = waveS[wv]; waveS[wv] = acc; acc += x; }
    }
    __syncthreads();
    const int base = waveS[wid] + (sc - ps);
    cumL[2 * t]     = base + e0;
    cumL[2 * t + 1] = base + e0 + e1;
    __syncthreads();

    for (int i = t; i < N_PED; i += 1024)
        out[2 * SEQ * N_PED + i] = (float)(cumL[labelL[i]] - 1);
}

extern "C" void kernel_launch(void* const* d_in, const int* in_sizes, int n_in,
                              void* d_out, int out_size, void* d_ws, size_t ws_size,
                              hipStream_t stream) {
    const float* v  = (const float*)d_in[0];
    const float* va = (const float*)d_in[1];
    float* out = (float*)d_out;
    char* ws = (char*)d_ws;

    int* cand = (int*)ws;                 // 8 KB
    int* mrA  = (int*)(ws + 8 * 1024);    // 8 KB

    col_kernel<<<N_PED / 8, 512, 0, stream>>>(va, v, cand, mrA, out);
    scan_kernel<<<1, 1024, 0, stream>>>(cand, mrA, out);
}